// Round 15
// baseline (25.323 us; speedup 1.0000x reference)
//
#include <hip/hip_runtime.h>

// B=8192, D=1024, C=90, K=16.
// R15 = R14's pipeline with the dots kernel moved to the MFMA pipe:
//  (1) bin_split (R14, proven): 180 blocks, per-class lists + counts.
//  (2) mfma_dots: block = (class, 16-sample unit); 4 waves = K-quarters.
//      Per wave: 8x mfma_f32_16x16x32_bf16 (A = 16 x-rows' K-slice, B =
//      16 sub-centers' K-slice, both converted f32->bf16 in-register).
//      C/D fragment layout (m89-verified: row=(lane>>4)*4+reg = sample,
//      col=lane&15 = k) is exactly the epilogue layout -> REDUCE16 and the
//      dots shuffle are eliminated. LDS f32x4 combine of the 4 K-quarters,
//      wave-0 epilogue (4x sample_loss16), one partial per block.
//      A/B k-slice loading uses one shared (lane-group,elem)->D-offset
//      bijection, so the dot is correct regardless of the HW's internal
//      k-permutation; only the M/N = lane&15 mappings matter.
//  (3) reduce_final: 768 partials -> mean. No atomics anywhere.

#define B_SAMP  8192
#define K_SUB   16
#define C_CLS   90
#define LISTCAP 192             // per-class capacity (mean 91, ~10 sigma)
#define F4_ROW  256             // float4 per D=1024 row
#define TSLOT   96              // 16-sample units per XCD group (worst ~91)
#define NBLK    (8 * TSLOT)     // 768
#define NPART   NBLK

// ws layout (bytes)
#define OFF_COUNTS 0            // 90 ints
#define OFF_LISTS  4096         // 90*192 ints
#define OFF_PART   (1u << 20)   // NPART floats

typedef __attribute__((ext_vector_type(8))) short bf16x8;  // 8 bf16 (4 VGPRs)
typedef __attribute__((ext_vector_type(4))) float f32x4;

// pack two f32 into one u32 of 2 bf16 (truncation; bias ~0.2% -> dot error
// ~1e-4, far under the 0.28 abs threshold). Shift form: guaranteed to compile.
__device__ __forceinline__ unsigned pk2(float hi, float lo) {
    return (__float_as_uint(hi) & 0xffff0000u) | (__float_as_uint(lo) >> 16);
}

// 16-lane-group epilogue (verified R6-R14): lane holds d for k=kk.
__device__ __forceinline__ float sample_loss16(float r, int kk)
{
    const float d = 1.0f - r;
    float S = d;
    S += __shfl_xor(S, 1, 64);
    S += __shfl_xor(S, 2, 64);
    S += __shfl_xor(S, 4, 64);
    S += __shfl_xor(S, 8, 64);
    float dmin = d;
    dmin = fminf(dmin, __shfl_xor(dmin, 1, 64));
    dmin = fminf(dmin, __shfl_xor(dmin, 2, 64));
    dmin = fminf(dmin, __shfl_xor(dmin, 4, 64));
    dmin = fminf(dmin, __shfl_xor(dmin, 8, 64));
    int cand = (d == dmin) ? kk : 99;      // first-min == jnp.argmin
    cand = min(cand, __shfl_xor(cand, 1, 64));
    cand = min(cand, __shfl_xor(cand, 2, 64));
    cand = min(cand, __shfl_xor(cand, 4, 64));
    cand = min(cand, __shfl_xor(cand, 8, 64));
    const float inv = 1.0f / S;
    float t = (kk == cand) ? (d * d * inv)            // term1
                           : ((1.0f - d * inv) * d);  // term2
    t += __shfl_xor(t, 1, 64);
    t += __shfl_xor(t, 2, 64);
    t += __shfl_xor(t, 4, 64);
    t += __shfl_xor(t, 8, 64);
    return t;
}

// ------- Kernel 1: split binning (R14 verbatim) -------
__global__ __launch_bounds__(256) void bin_split(
    const int* __restrict__ labels,
    int*       __restrict__ counts,
    int*       __restrict__ lists)
{
    const int c    = blockIdx.x >> 1;
    const int h    = blockIdx.x & 1;
    const int tid  = threadIdx.x;
    const int wave = tid >> 6;
    const int lane = tid & 63;
    __shared__ int wcnt[4];
    __shared__ int b0_sh;

    const int4* lv = reinterpret_cast<const int4*>(labels);

    if (h == 1) {
        int c0 = 0;
#pragma unroll
        for (int it = 0; it < 4; ++it) {
            const int4 l4 = lv[wave * 256 + it * 64 + lane];
            c0 += (l4.x == c) + (l4.y == c) + (l4.z == c) + (l4.w == c);
        }
#pragma unroll
        for (int off = 32; off > 0; off >>= 1) c0 += __shfl_xor(c0, off, 64);
        if (lane == 0) wcnt[wave] = c0;
        __syncthreads();
        if (tid == 0) b0_sh = wcnt[0] + wcnt[1] + wcnt[2] + wcnt[3];
        __syncthreads();
    } else {
        if (tid == 0) b0_sh = 0;
        __syncthreads();
    }
    const int hbase = b0_sh;

    const int4* hv = lv + h * 1024;

    int4 seg[4];
    int cnt = 0;
#pragma unroll
    for (int it = 0; it < 4; ++it) {
        seg[it] = hv[wave * 256 + it * 64 + lane];
        cnt += (seg[it].x == c) + (seg[it].y == c) + (seg[it].z == c) + (seg[it].w == c);
    }
#pragma unroll
    for (int off = 32; off > 0; off >>= 1) cnt += __shfl_xor(cnt, off, 64);
    if (lane == 0) wcnt[wave] = cnt;
    __syncthreads();

    int base = hbase;
    for (int w = 0; w < wave; ++w) base += wcnt[w];
    const int htotal = wcnt[0] + wcnt[1] + wcnt[2] + wcnt[3];

#pragma unroll
    for (int it = 0; it < 4; ++it) {
        const int idx0 = h * 4096 + (wave * 256 + it * 64 + lane) * 4;
        const int ls[4] = { seg[it].x, seg[it].y, seg[it].z, seg[it].w };
#pragma unroll
        for (int u = 0; u < 4; ++u) {
            const bool hit = (ls[u] == c);
            const unsigned long long m = __ballot(hit);
            if (hit) {
                const int p = base + (int)__popcll(m & ((1ull << lane) - 1ull));
                if (p < LISTCAP) lists[c * LISTCAP + p] = idx0 + u;
            }
            base += (int)__popcll(m);
        }
    }
    if (h == 1 && tid == 0) {
        const int total = hbase + htotal;
        counts[c] = (total <= LISTCAP) ? total : LISTCAP;
    }
}

// ------- Kernel 2: MFMA dots + in-block loss -------
__global__ __launch_bounds__(256) void mfma_dots(
    const float* __restrict__ x,
    const float* __restrict__ centers,
    const int*   __restrict__ counts,
    const int*   __restrict__ lists,
    float*       __restrict__ partials)
{
    const int b    = blockIdx.x;
    const int g    = b & 7;                 // XCD group: classes c == g (mod 8)
    const int t    = b >> 3;                // 16-sample unit within group
    const int tid  = threadIdx.x;
    const int wv   = tid >> 6;              // K-quarter 0..3 (256 D each)
    const int lane = tid & 63;
    const int g4   = lane >> 4;             // k-subgroup within fragment
    const int sl   = lane & 15;             // A: sample slot / B: sub-center

    __shared__ f32x4 sacc[4][64];           // 4 KB

    // ---- 16-lane register scan: unit t -> (class, base) ----
    const int cl  = g + 8 * lane;
    const int n_l = (lane < 12 && cl < C_CLS) ? counts[cl] : 0;
    const int u_l = (n_l + 15) >> 4;        // 16-sample units in this class
    int inc = u_l;
#pragma unroll
    for (int off = 1; off < 16; off <<= 1) {
        const int v = __shfl_up(inc, off, 64);
        if (lane >= off) inc += v;
    }
    const int Qg  = __shfl(inc, 15, 64);
    const int exc = inc - u_l;

    if (t >= Qg) {                          // dead block (uniform, pre-barrier)
        if (tid == 0) partials[b] = 0.0f;
        return;
    }

    const bool hit = (lane < 16) && (u_l > 0) && (t >= exc) && (t < inc);
    const unsigned long long m = __ballot(hit);
    const int ls   = (int)__ffsll(m) - 1;
    const int cls  = g + 8 * ls;
    const int uoff = t - __shfl(exc, ls, 64);
    const int cntc = __shfl(n_l, ls, 64);   // >= 1 when selected
    const int base = uoff * 16;

    // per-lane sample id (clamped to last valid; padded samples gated later)
    const int sid = base + sl;
    const int idx = lists[cls * LISTCAP + ((sid < cntc) ? sid : (cntc - 1))];

    const float4* xrow = reinterpret_cast<const float4*>(x) + (size_t)idx * F4_ROW;
    const float4* crow = reinterpret_cast<const float4*>(centers)
                       + (size_t)(cls * K_SUB + sl) * F4_ROW;

    f32x4 acc = {0.0f, 0.0f, 0.0f, 0.0f};

    // 8 MFMA steps over this wave's K-quarter. Per step, lane (g4,sl) loads
    // D-offsets wv*256 + s*32 + g4*4 + {0..3} and +16 from its A-row and
    // B-row -- one bijective k-slice shared by A and B.
#pragma unroll
    for (int s = 0; s < 8; ++s) {
        const int o = wv * 64 + s * 8 + g4;
        const float4 a0 = xrow[o], a1 = xrow[o + 4];
        const float4 c0 = crow[o], c1 = crow[o + 4];
        union { unsigned u[4]; bf16x8 v; } fa, fb;
        fa.u[0] = pk2(a0.y, a0.x); fa.u[1] = pk2(a0.w, a0.z);
        fa.u[2] = pk2(a1.y, a1.x); fa.u[3] = pk2(a1.w, a1.z);
        fb.u[0] = pk2(c0.y, c0.x); fb.u[1] = pk2(c0.w, c0.z);
        fb.u[2] = pk2(c1.y, c1.x); fb.u[3] = pk2(c1.w, c1.z);
        acc = __builtin_amdgcn_mfma_f32_16x16x32_bf16(fa.v, fb.v, acc, 0, 0, 0);
    }

    sacc[wv][lane] = acc;
    __syncthreads();

    // ---- wave-0 epilogue: combine K-quarters; D layout gives (sample,k)
    // directly: reg r -> sample base+4*g4+r, col sl = k. ----
    if (wv == 0) {
        const f32x4 rr = sacc[0][lane] + sacc[1][lane]
                       + sacc[2][lane] + sacc[3][lane];
        float wl = 0.0f;
#pragma unroll
        for (int r = 0; r < 4; ++r) {
            const int smp = base + 4 * g4 + r;          // group-uniform gate
            const float gate = (smp < cntc) ? 1.0f : 0.0f;
            wl += sample_loss16(rr[r], sl) * gate;
        }
        wl += __shfl_xor(wl, 16, 64);       // sum the 4 sample-groups
        wl += __shfl_xor(wl, 32, 64);
        if (lane == 0) partials[b] = wl;
    }
}

// ---------------- Kernel 3: final mean over NPART partials ----------------
__global__ __launch_bounds__(256) void reduce_final(
    const float* __restrict__ partials,
    float*       __restrict__ out)
{
    const int tid  = threadIdx.x;
    const int wave = tid >> 6;
    const int lane = tid & 63;
    float s = 0.0f;
#pragma unroll
    for (int r = 0; r < NPART / 256; ++r) s += partials[r * 256 + tid];
#pragma unroll
    for (int off = 32; off > 0; off >>= 1) s += __shfl_xor(s, off, 64);
    __shared__ float w[4];
    if (lane == 0) w[wave] = s;
    __syncthreads();
    if (tid == 0)
        out[0] = (w[0] + w[1] + w[2] + w[3]) * (1.0f / (float)B_SAMP);
}

extern "C" void kernel_launch(void* const* d_in, const int* in_sizes, int n_in,
                              void* d_out, int out_size, void* d_ws, size_t ws_size,
                              hipStream_t stream)
{
    const float* x       = (const float*)d_in[0];
    const int*   labels  = (const int*)  d_in[1];
    const float* centers = (const float*)d_in[2];
    float*       out     = (float*)d_out;
    char*        ws      = (char*)d_ws;

    int*   counts = (int*)  (ws + OFF_COUNTS);
    int*   lists  = (int*)  (ws + OFF_LISTS);
    float* parts  = (float*)(ws + OFF_PART);

    bin_split   <<<C_CLS * 2, 256, 0, stream>>>(labels, counts, lists);
    mfma_dots   <<<NBLK,      256, 0, stream>>>(x, centers, counts, lists, parts);
    reduce_final<<<1,         256, 0, stream>>>(parts, out);
}

// Round 16
// 24.016 us; speedup vs baseline: 1.0544x; 1.0544x over previous
//
#include <hip/hip_runtime.h>

// B=8192, D=1024, C=90, K=16.
// R16 = R14 pipeline (best, 22.9us) with the dots kernel upgraded to OCTETs:
//  (1) bin_split (R14 verbatim): 180 blocks, per-class lists + counts.
//  (2) octo_dots: block = 8 same-class samples; wave = D-quarter. Each
//      center float4 read feeds 8 samples -> centers L2 traffic halves vs
//      the quad version (67 MB vs 133 MB). 8 x-loads in flight per wave.
//      NO atomic tail (R6/R11/R13: proven 2-4x toxic) - per-wave partials.
//  (3) reduce_final (R14 verbatim): 3072 partials, 1024 threads.

#define B_SAMP  8192
#define K_SUB   16
#define C_CLS   90
#define LISTCAP 192             // per-class capacity (mean 91, ~10 sigma)
#define F4_ROW  256             // float4 per D=1024 row
#define TSLOT   192             // octet slots per XCD group (worst ~140)
#define NBLK    (8 * TSLOT)     // 1536
#define NPART   (NBLK * 2)      // 3072

// ws layout (bytes)
#define OFF_COUNTS 0            // 90 ints
#define OFF_LISTS  4096         // 90*192 ints
#define OFF_PART   (1u << 20)   // NPART floats

template <int CTRL>
__device__ __forceinline__ float dpp_qperm(float v) {
    return __int_as_float(__builtin_amdgcn_update_dpp(
        0, __float_as_int(v), CTRL, 0xF, 0xF, true));
}

// 16-lane-group epilogue (verified R6-R15): lane holds d for k=kk.
__device__ __forceinline__ float sample_loss16(float r, int kk)
{
    const float d = 1.0f - r;
    float S = d;
    S += __shfl_xor(S, 1, 64);
    S += __shfl_xor(S, 2, 64);
    S += __shfl_xor(S, 4, 64);
    S += __shfl_xor(S, 8, 64);
    float dmin = d;
    dmin = fminf(dmin, __shfl_xor(dmin, 1, 64));
    dmin = fminf(dmin, __shfl_xor(dmin, 2, 64));
    dmin = fminf(dmin, __shfl_xor(dmin, 4, 64));
    dmin = fminf(dmin, __shfl_xor(dmin, 8, 64));
    int cand = (d == dmin) ? kk : 99;      // first-min == jnp.argmin
    cand = min(cand, __shfl_xor(cand, 1, 64));
    cand = min(cand, __shfl_xor(cand, 2, 64));
    cand = min(cand, __shfl_xor(cand, 4, 64));
    cand = min(cand, __shfl_xor(cand, 8, 64));
    const float inv = 1.0f / S;
    float t = (kk == cand) ? (d * d * inv)            // term1
                           : ((1.0f - d * inv) * d);  // term2
    t += __shfl_xor(t, 1, 64);
    t += __shfl_xor(t, 2, 64);
    t += __shfl_xor(t, 4, 64);
    t += __shfl_xor(t, 8, 64);
    return t;
}

// ------- Kernel 1: split binning (R14 verbatim) -------
__global__ __launch_bounds__(256) void bin_split(
    const int* __restrict__ labels,
    int*       __restrict__ counts,
    int*       __restrict__ lists)
{
    const int c    = blockIdx.x >> 1;
    const int h    = blockIdx.x & 1;
    const int tid  = threadIdx.x;
    const int wave = tid >> 6;
    const int lane = tid & 63;
    __shared__ int wcnt[4];
    __shared__ int b0_sh;

    const int4* lv = reinterpret_cast<const int4*>(labels);

    if (h == 1) {
        int c0 = 0;
#pragma unroll
        for (int it = 0; it < 4; ++it) {
            const int4 l4 = lv[wave * 256 + it * 64 + lane];
            c0 += (l4.x == c) + (l4.y == c) + (l4.z == c) + (l4.w == c);
        }
#pragma unroll
        for (int off = 32; off > 0; off >>= 1) c0 += __shfl_xor(c0, off, 64);
        if (lane == 0) wcnt[wave] = c0;
        __syncthreads();
        if (tid == 0) b0_sh = wcnt[0] + wcnt[1] + wcnt[2] + wcnt[3];
        __syncthreads();
    } else {
        if (tid == 0) b0_sh = 0;
        __syncthreads();
    }
    const int hbase = b0_sh;

    const int4* hv = lv + h * 1024;

    int4 seg[4];
    int cnt = 0;
#pragma unroll
    for (int it = 0; it < 4; ++it) {
        seg[it] = hv[wave * 256 + it * 64 + lane];
        cnt += (seg[it].x == c) + (seg[it].y == c) + (seg[it].z == c) + (seg[it].w == c);
    }
#pragma unroll
    for (int off = 32; off > 0; off >>= 1) cnt += __shfl_xor(cnt, off, 64);
    if (lane == 0) wcnt[wave] = cnt;
    __syncthreads();

    int base = hbase;
    for (int w = 0; w < wave; ++w) base += wcnt[w];
    const int htotal = wcnt[0] + wcnt[1] + wcnt[2] + wcnt[3];

#pragma unroll
    for (int it = 0; it < 4; ++it) {
        const int idx0 = h * 4096 + (wave * 256 + it * 64 + lane) * 4;
        const int ls[4] = { seg[it].x, seg[it].y, seg[it].z, seg[it].w };
#pragma unroll
        for (int u = 0; u < 4; ++u) {
            const bool hit = (ls[u] == c);
            const unsigned long long m = __ballot(hit);
            if (hit) {
                const int p = base + (int)__popcll(m & ((1ull << lane) - 1ull));
                if (p < LISTCAP) lists[c * LISTCAP + p] = idx0 + u;
            }
            base += (int)__popcll(m);
        }
    }
    if (h == 1 && tid == 0) {
        const int total = hbase + htotal;
        counts[c] = (total <= LISTCAP) ? total : LISTCAP;
    }
}

// ------- Kernel 2: octet dots + in-block loss (no atomics) -------
__global__ __launch_bounds__(256) void octo_dots(
    const float* __restrict__ x,
    const float* __restrict__ centers,
    const int*   __restrict__ counts,
    const int*   __restrict__ lists,
    float*       __restrict__ partials)
{
    const int b    = blockIdx.x;
    const int g    = b & 7;                 // XCD group: classes c == g (mod 8)
    const int t    = b >> 3;                // octet slot within group
    const int tid  = threadIdx.x;
    const int wv   = tid >> 6;              // D-quarter index 0..3
    const int lane = tid & 63;

    __shared__ float sdots[4][8][17];       // [quarter][sample][k], padded

    // ---- 16-lane register scan: octet t -> (class, offset) ----
    const int cl  = g + 8 * lane;           // lane<12 relevant
    const int n_l = (lane < 12 && cl < C_CLS) ? counts[cl] : 0;
    const int o_l = (n_l + 7) >> 3;         // octets in this class
    int inc = o_l;
#pragma unroll
    for (int off = 1; off < 16; off <<= 1) {
        const int v = __shfl_up(inc, off, 64);
        if (lane >= off) inc += v;
    }
    const int Qg  = __shfl(inc, 15, 64);    // total octets in group
    const int exc = inc - o_l;

    if (t >= Qg) {                          // dead block (uniform, pre-barrier)
        if (tid < 2) partials[b * 2 + tid] = 0.0f;
        return;
    }

    const bool hit = (lane < 16) && (o_l > 0) && (t >= exc) && (t < inc);
    const unsigned long long m = __ballot(hit);
    const int ls   = (int)__ffsll(m) - 1;
    const int cls  = g + 8 * ls;
    const int ooff = t - __shfl(exc, ls, 64);
    const int cntc = __shfl(n_l, ls, 64);
    const int base = ooff * 8;              // < cntc always

    const int4* lp = reinterpret_cast<const int4*>(lists + cls * LISTCAP + base);
    const int4 g0 = lp[0];
    const int4 g1 = lp[1];
    int id[8];
    id[0] = g0.x;
    id[1] = (base + 1 < cntc) ? g0.y : g0.x;
    id[2] = (base + 2 < cntc) ? g0.z : g0.x;
    id[3] = (base + 3 < cntc) ? g0.w : g0.x;
    id[4] = (base + 4 < cntc) ? g1.x : g0.x;
    id[5] = (base + 5 < cntc) ? g1.y : g0.x;
    id[6] = (base + 6 < cntc) ? g1.z : g0.x;
    id[7] = (base + 7 < cntc) ? g1.w : g0.x;

    // x: this wave's D-quarter of the 8 rows (8 loads, all in flight)
    const float4* xv = reinterpret_cast<const float4*>(x) + (wv * 64 + lane);
    float4 xr[8];
#pragma unroll
    for (int s = 0; s < 8; ++s)
        xr[s] = xv[(size_t)id[s] * F4_ROW];

    const float4* cb = reinterpret_cast<const float4*>(centers)
                     + ((size_t)cls * K_SUB * F4_ROW + wv * 64 + lane);

    const bool b0 = (lane & 1) != 0;
    const bool b1 = (lane & 2) != 0;
    const bool b2 = (lane & 4) != 0;
    const bool b3 = (lane & 8) != 0;
    const int kmap = 8 * (lane & 1) + 4 * ((lane >> 1) & 1)
                   + 2 * ((lane >> 2) & 1) + ((lane >> 3) & 1);

#define REDUCE16(A, OUT)                                                      \
    {                                                                         \
        _Pragma("unroll")                                                     \
        for (int jj = 0; jj < 8; ++jj) {                                      \
            const float send = b0 ? A[jj] : A[jj + 8];                        \
            const float recv = dpp_qperm<0xB1>(send);       /* xor 1 */       \
            A[jj] = (b0 ? A[jj + 8] : A[jj]) + recv;                          \
        }                                                                     \
        _Pragma("unroll")                                                     \
        for (int jj = 0; jj < 4; ++jj) {                                      \
            const float send = b1 ? A[jj] : A[jj + 4];                        \
            const float recv = dpp_qperm<0x4E>(send);       /* xor 2 */       \
            A[jj] = (b1 ? A[jj + 4] : A[jj]) + recv;                          \
        }                                                                     \
        _Pragma("unroll")                                                     \
        for (int jj = 0; jj < 2; ++jj) {                                      \
            const float send = b2 ? A[jj] : A[jj + 2];                        \
            const float recv = __shfl_xor(send, 4, 64);                       \
            A[jj] = (b2 ? A[jj + 2] : A[jj]) + recv;                          \
        }                                                                     \
        {                                                                     \
            const float send = b3 ? A[0] : A[1];                              \
            const float recv = __shfl_xor(send, 8, 64);                      \
            A[0] = (b3 ? A[1] : A[0]) + recv;                                 \
        }                                                                     \
        A[0] += __shfl_xor(A[0], 16, 64);                                     \
        A[0] += __shfl_xor(A[0], 32, 64);                                     \
        OUT = A[0];                                                           \
    }

    // 4 k-groups; per group: 4 center loads feed ALL 8 samples.
#pragma unroll
    for (int kq = 0; kq < 4; ++kq) {
        float4 q4[4];
#pragma unroll
        for (int kk = 0; kk < 4; ++kk)
            q4[kk] = cb[(kq * 4 + kk) * F4_ROW];

        float A[16];
#pragma unroll
        for (int kk = 0; kk < 4; ++kk) {
#pragma unroll
            for (int s = 0; s < 4; ++s) {
                float v = xr[s].x * q4[kk].x;
                v = fmaf(xr[s].y, q4[kk].y, v);
                v = fmaf(xr[s].z, q4[kk].z, v);
                v = fmaf(xr[s].w, q4[kk].w, v);
                A[s * 4 + kk] = v;
            }
        }
        float rA;
        REDUCE16(A, rA)
        if (lane < 16) sdots[wv][kmap >> 2][kq * 4 + (kmap & 3)] = rA;

        float B[16];
#pragma unroll
        for (int kk = 0; kk < 4; ++kk) {
#pragma unroll
            for (int s = 0; s < 4; ++s) {
                float v = xr[4 + s].x * q4[kk].x;
                v = fmaf(xr[4 + s].y, q4[kk].y, v);
                v = fmaf(xr[4 + s].z, q4[kk].z, v);
                v = fmaf(xr[4 + s].w, q4[kk].w, v);
                B[s * 4 + kk] = v;
            }
        }
        float rB;
        REDUCE16(B, rB)
        if (lane < 16) sdots[wv][4 + (kmap >> 2)][kq * 4 + (kmap & 3)] = rB;
    }
#undef REDUCE16

    __syncthreads();

    // epilogue: waves 0-1 handle 4 samples each (16 lanes per sample);
    // base/cntc are block-uniform -> gate computed directly (no LDS).
    if (wv < 2) {
        const int s  = wv * 4 + (lane >> 4);
        const int kk = lane & 15;
        const float r = sdots[0][s][kk] + sdots[1][s][kk]
                      + sdots[2][s][kk] + sdots[3][s][kk];
        const float gate = (base + s < cntc) ? 1.0f : 0.0f;
        float wl = sample_loss16(r, kk) * gate;
        wl += __shfl_xor(wl, 16, 64);
        wl += __shfl_xor(wl, 32, 64);
        if (lane == 0) partials[b * 2 + wv] = wl;
    }
}

// ---------------- Kernel 3: final mean, 1024 threads (R14 verbatim) ----------------
__global__ __launch_bounds__(1024) void reduce_final(
    const float* __restrict__ partials,
    float*       __restrict__ out)
{
    const int tid  = threadIdx.x;
    const int wave = tid >> 6;
    const int lane = tid & 63;
    float s = 0.0f;
#pragma unroll
    for (int r = 0; r < NPART / 1024; ++r) s += partials[r * 1024 + tid];
#pragma unroll
    for (int off = 32; off > 0; off >>= 1) s += __shfl_xor(s, off, 64);
    __shared__ float w[16];
    if (lane == 0) w[wave] = s;
    __syncthreads();
    if (wave == 0) {
        float v = (lane < 16) ? w[lane] : 0.0f;
#pragma unroll
        for (int off = 8; off > 0; off >>= 1) v += __shfl_xor(v, off, 64);
        if (lane == 0) out[0] = v * (1.0f / (float)B_SAMP);
    }
}

extern "C" void kernel_launch(void* const* d_in, const int* in_sizes, int n_in,
                              void* d_out, int out_size, void* d_ws, size_t ws_size,
                              hipStream_t stream)
{
    const float* x       = (const float*)d_in[0];
    const int*   labels  = (const int*)  d_in[1];
    const float* centers = (const float*)d_in[2];
    float*       out     = (float*)d_out;
    char*        ws      = (char*)d_ws;

    int*   counts = (int*)  (ws + OFF_COUNTS);
    int*   lists  = (int*)  (ws + OFF_LISTS);
    float* parts  = (float*)(ws + OFF_PART);

    bin_split   <<<C_CLS * 2, 256,  0, stream>>>(labels, counts, lists);
    octo_dots   <<<NBLK,      256,  0, stream>>>(x, centers, counts, lists, parts);
    reduce_final<<<1,         1024, 0, stream>>>(parts, out);
}

// Round 17
// 23.059 us; speedup vs baseline: 1.0982x; 1.0415x over previous
//
#include <hip/hip_runtime.h>

// B=8192, D=1024, C=90, K=16.
// R17 = R14 (best, 22.9us) with the reduce dispatch FOLDED into the dots
// kernel via a NaN-sentinel producer/consumer (no same-address RMW tail --
// that pattern was 2-4x toxic in R6/R11/R13; spread atomic STORES are not):
//  (1) bin_split (R14 verbatim) + qNaN-fill of partials[3072] (h==0 blocks).
//  (2) quad_dots: R14 verbatim, grid NBLK+1. Blocks [0,NBLK) write their 2
//      partial slots with relaxed agent-scope atomic stores. Block NBLK
//      (dispatched last) spin-reads every slot until non-NaN and computes
//      the mean in a fixed order -> deterministic. Reducer only reads ->
//      no deadlock; per-sample losses are finite (S>0) so NaN is safe.

#define B_SAMP  8192
#define K_SUB   16
#define C_CLS   90
#define LISTCAP 192             // per-class capacity (mean 91, ~10 sigma)
#define F4_ROW  256             // float4 per D=1024 row
#define TSLOT   192             // block slots per XCD group (2 quads each)
#define NBLK    (8 * TSLOT)     // 1536
#define NPART   (NBLK * 2)      // 3072
#define QNAN_U  0x7fc00000u

// ws layout (bytes)
#define OFF_COUNTS 0            // 90 ints
#define OFF_LISTS  4096         // 90*192 ints
#define OFF_PART   (1u << 20)   // NPART floats

template <int CTRL>
__device__ __forceinline__ float dpp_qperm(float v) {
    return __int_as_float(__builtin_amdgcn_update_dpp(
        0, __float_as_int(v), CTRL, 0xF, 0xF, true));
}

__device__ __forceinline__ float dot8(float4 q0, float4 q1, float4 y0, float4 y1)
{
    float t = 0.0f;
    t = fmaf(y0.x, q0.x, t); t = fmaf(y0.y, q0.y, t);
    t = fmaf(y0.z, q0.z, t); t = fmaf(y0.w, q0.w, t);
    t = fmaf(y1.x, q1.x, t); t = fmaf(y1.y, q1.y, t);
    t = fmaf(y1.z, q1.z, t); t = fmaf(y1.w, q1.w, t);
    return t;
}

__device__ __forceinline__ void part_store(float* p, float v) {
    __hip_atomic_store(p, v, __ATOMIC_RELAXED, __HIP_MEMORY_SCOPE_AGENT);
}

// 16-lane-group epilogue (verified R6-R16).
__device__ __forceinline__ float sample_loss16(float r, int kk)
{
    const float d = 1.0f - r;
    float S = d;
    S += __shfl_xor(S, 1, 64);
    S += __shfl_xor(S, 2, 64);
    S += __shfl_xor(S, 4, 64);
    S += __shfl_xor(S, 8, 64);
    float dmin = d;
    dmin = fminf(dmin, __shfl_xor(dmin, 1, 64));
    dmin = fminf(dmin, __shfl_xor(dmin, 2, 64));
    dmin = fminf(dmin, __shfl_xor(dmin, 4, 64));
    dmin = fminf(dmin, __shfl_xor(dmin, 8, 64));
    int cand = (d == dmin) ? kk : 99;      // first-min == jnp.argmin
    cand = min(cand, __shfl_xor(cand, 1, 64));
    cand = min(cand, __shfl_xor(cand, 2, 64));
    cand = min(cand, __shfl_xor(cand, 4, 64));
    cand = min(cand, __shfl_xor(cand, 8, 64));
    const float inv = 1.0f / S;
    float t = (kk == cand) ? (d * d * inv)            // term1
                           : ((1.0f - d * inv) * d);  // term2
    t += __shfl_xor(t, 1, 64);
    t += __shfl_xor(t, 2, 64);
    t += __shfl_xor(t, 4, 64);
    t += __shfl_xor(t, 8, 64);
    return t;
}

// ------- Kernel 1: split binning (R14) + partials qNaN fill -------
__global__ __launch_bounds__(256) void bin_split(
    const int* __restrict__ labels,
    int*       __restrict__ counts,
    int*       __restrict__ lists,
    float*     __restrict__ partials)
{
    const int c    = blockIdx.x >> 1;
    const int h    = blockIdx.x & 1;
    const int tid  = threadIdx.x;
    const int wave = tid >> 6;
    const int lane = tid & 63;
    __shared__ int wcnt[4];
    __shared__ int b0_sh;

    // h==0 blocks: qNaN-fill this class's slice of partials (35 slots)
    if (h == 0 && tid < 35) {
        const int i = c * 35 + tid;
        if (i < NPART)
            reinterpret_cast<unsigned*>(partials)[i] = QNAN_U;
    }

    const int4* lv = reinterpret_cast<const int4*>(labels);

    if (h == 1) {
        int c0 = 0;
#pragma unroll
        for (int it = 0; it < 4; ++it) {
            const int4 l4 = lv[wave * 256 + it * 64 + lane];
            c0 += (l4.x == c) + (l4.y == c) + (l4.z == c) + (l4.w == c);
        }
#pragma unroll
        for (int off = 32; off > 0; off >>= 1) c0 += __shfl_xor(c0, off, 64);
        if (lane == 0) wcnt[wave] = c0;
        __syncthreads();
        if (tid == 0) b0_sh = wcnt[0] + wcnt[1] + wcnt[2] + wcnt[3];
        __syncthreads();
    } else {
        if (tid == 0) b0_sh = 0;
        __syncthreads();
    }
    const int hbase = b0_sh;

    const int4* hv = lv + h * 1024;

    int4 seg[4];
    int cnt = 0;
#pragma unroll
    for (int it = 0; it < 4; ++it) {
        seg[it] = hv[wave * 256 + it * 64 + lane];
        cnt += (seg[it].x == c) + (seg[it].y == c) + (seg[it].z == c) + (seg[it].w == c);
    }
#pragma unroll
    for (int off = 32; off > 0; off >>= 1) cnt += __shfl_xor(cnt, off, 64);
    if (lane == 0) wcnt[wave] = cnt;
    __syncthreads();

    int base = hbase;
    for (int w = 0; w < wave; ++w) base += wcnt[w];
    const int htotal = wcnt[0] + wcnt[1] + wcnt[2] + wcnt[3];

#pragma unroll
    for (int it = 0; it < 4; ++it) {
        const int idx0 = h * 4096 + (wave * 256 + it * 64 + lane) * 4;
        const int ls[4] = { seg[it].x, seg[it].y, seg[it].z, seg[it].w };
#pragma unroll
        for (int u = 0; u < 4; ++u) {
            const bool hit = (ls[u] == c);
            const unsigned long long m = __ballot(hit);
            if (hit) {
                const int p = base + (int)__popcll(m & ((1ull << lane) - 1ull));
                if (p < LISTCAP) lists[c * LISTCAP + p] = idx0 + u;
            }
            base += (int)__popcll(m);
        }
    }
    if (h == 1 && tid == 0) {
        const int total = hbase + htotal;
        counts[c] = (total <= LISTCAP) ? total : LISTCAP;
    }
}

// -------- Kernel 2: R14's quad_dots + in-kernel sentinel reduce --------
__global__ __launch_bounds__(256) void quad_dots(
    const float* __restrict__ x,
    const float* __restrict__ centers,
    const int*   __restrict__ counts,
    const int*   __restrict__ lists,
    float*       __restrict__ partials,
    float*       __restrict__ out)
{
    const int b = blockIdx.x;
    const int tid  = threadIdx.x;
    const int wv   = tid >> 6;
    const int lane = tid & 63;

    // ---- reducer block (dispatched last): spin on sentinels, fixed-order sum ----
    if (b == NBLK) {
        float s = 0.0f;
        for (int i = tid; i < NPART; i += 256) {
            float v;
            do {
                v = __hip_atomic_load(&partials[i], __ATOMIC_RELAXED,
                                      __HIP_MEMORY_SCOPE_AGENT);
            } while (v != v);               // spin while qNaN sentinel
            s += v;
        }
#pragma unroll
        for (int off = 32; off > 0; off >>= 1) s += __shfl_xor(s, off, 64);
        __shared__ float w[4];
        if (lane == 0) w[wv] = s;
        __syncthreads();
        if (tid == 0)
            out[0] = (w[0] + w[1] + w[2] + w[3]) * (1.0f / (float)B_SAMP);
        return;
    }

    const int g    = b & 7;                 // XCD group: classes c == g (mod 8)
    const int t    = b >> 3;
    const int pair = wv >> 1;               // 0 or 1: which quad
    const int h    = wv & 1;                // D-half

    __shared__ float sdots[4][4][16];       // [wave][sample][k]
    __shared__ float sgate[2][4];           // [pair][sample]

    // ---- 16-lane register scan: quad j -> (class, offset) ----
    const int cl  = g + 8 * lane;                       // lane<12 relevant
    const int n_l = (lane < 12 && cl < C_CLS) ? counts[cl] : 0;
    const int q_l = (n_l + 3) >> 2;                     // quads in this class
    int inc = q_l;
#pragma unroll
    for (int off = 1; off < 16; off <<= 1) {
        const int v = __shfl_up(inc, off, 64);
        if (lane >= off) inc += v;
    }
    const int Qg  = __shfl(inc, 15, 64);                // total quads in group
    const int exc = inc - q_l;

    const int j = 2 * t + pair;                         // this pair's quad id

    if (2 * t >= Qg) {                                  // dead block (uniform)
        if (tid < 2) part_store(&partials[b * 2 + tid], 0.0f);
        return;
    }

    const bool livepair = (j < Qg);                     // wave-uniform

    if (livepair) {
        const bool hit = (lane < 16) && (q_l > 0) && (j >= exc) && (j < inc);
        const unsigned long long m = __ballot(hit);
        const int ls   = (int)__ffsll(m) - 1;
        const int cls  = g + 8 * ls;
        const int qoff = j - __shfl(exc, ls, 64);
        const int cntc = __shfl(n_l, ls, 64);
        const int base = qoff * 4;                      // < cntc always

        const int4 grp = *reinterpret_cast<const int4*>(lists + cls * LISTCAP + base);
        int id[4];
        id[0] = grp.x;
        id[1] = (base + 1 < cntc) ? grp.y : grp.x;
        id[2] = (base + 2 < cntc) ? grp.z : grp.x;
        id[3] = (base + 3 < cntc) ? grp.w : grp.x;

        // x rows: this wave's D-half only -> x fetched exactly once per row.
        const float4* xv = reinterpret_cast<const float4*>(x);
        float4 xr[4][2];
#pragma unroll
        for (int s = 0; s < 4; ++s) {
            const size_t xo = (size_t)id[s] * F4_ROW + h * 128;
            xr[s][0] = xv[xo + lane];
            xr[s][1] = xv[xo + 64 + lane];
        }

        const float4* cb = reinterpret_cast<const float4*>(centers)
                         + (size_t)cls * (K_SUB * F4_ROW) + h * 128 + lane;

        const bool b0 = (lane & 1) != 0;
        const bool b1 = (lane & 2) != 0;
        const bool b2 = (lane & 4) != 0;
        const bool b3 = (lane & 8) != 0;
        const int kmap = 8 * (lane & 1) + 4 * ((lane >> 1) & 1)
                       + 2 * ((lane >> 2) & 1) + ((lane >> 3) & 1);

#define REDUCE16(A, OUT)                                                      \
    {                                                                         \
        _Pragma("unroll")                                                     \
        for (int jj = 0; jj < 8; ++jj) {                                      \
            const float send = b0 ? A[jj] : A[jj + 8];                        \
            const float recv = dpp_qperm<0xB1>(send);       /* xor 1 */       \
            A[jj] = (b0 ? A[jj + 8] : A[jj]) + recv;                          \
        }                                                                     \
        _Pragma("unroll")                                                     \
        for (int jj = 0; jj < 4; ++jj) {                                      \
            const float send = b1 ? A[jj] : A[jj + 4];                        \
            const float recv = dpp_qperm<0x4E>(send);       /* xor 2 */       \
            A[jj] = (b1 ? A[jj + 4] : A[jj]) + recv;                          \
        }                                                                     \
        _Pragma("unroll")                                                     \
        for (int jj = 0; jj < 2; ++jj) {                                      \
            const float send = b2 ? A[jj] : A[jj + 2];                        \
            const float recv = __shfl_xor(send, 4, 64);                       \
            A[jj] = (b2 ? A[jj + 2] : A[jj]) + recv;                          \
        }                                                                     \
        {                                                                     \
            const float send = b3 ? A[0] : A[1];                              \
            const float recv = __shfl_xor(send, 8, 64);                       \
            A[0] = (b3 ? A[1] : A[0]) + recv;                                 \
        }                                                                     \
        A[0] += __shfl_xor(A[0], 16, 64);                                     \
        A[0] += __shfl_xor(A[0], 32, 64);                                     \
        OUT = A[0];                                                           \
    }

        // 4 k-groups: only 16 accumulators live at a time (low VGPR).
#pragma unroll
        for (int kq = 0; kq < 4; ++kq) {
            float A[16];
#pragma unroll
            for (int kk = 0; kk < 4; ++kk) {
                const int k = kq * 4 + kk;
                const float4 q0 = cb[k * F4_ROW];
                const float4 q1 = cb[k * F4_ROW + 64];
                A[0 * 4 + kk] = dot8(q0, q1, xr[0][0], xr[0][1]);
                A[1 * 4 + kk] = dot8(q0, q1, xr[1][0], xr[1][1]);
                A[2 * 4 + kk] = dot8(q0, q1, xr[2][0], xr[2][1]);
                A[3 * 4 + kk] = dot8(q0, q1, xr[3][0], xr[3][1]);
            }
            float r;
            REDUCE16(A, r)
            if (lane < 16) sdots[wv][kmap >> 2][kq * 4 + (kmap & 3)] = r;
        }
#undef REDUCE16

        if (h == 0 && lane < 4)
            sgate[pair][lane] = (base + lane < cntc) ? 1.0f : 0.0f;
    } else {
        // dead pair: zero its sdots half + gates, then join the barrier
        if (lane < 16) {
#pragma unroll
            for (int s = 0; s < 4; ++s) sdots[wv][s][lane] = 0.0f;
        }
        if (h == 0 && lane < 4) sgate[pair][lane] = 0.0f;
    }

    __syncthreads();

    // epilogue: wave 0 -> pair 0, wave 1 -> pair 1
    if (wv < 2) {
        const int s  = lane >> 4;
        const int kk = lane & 15;
        const float r = sdots[wv * 2][s][kk] + sdots[wv * 2 + 1][s][kk];
        float wl = sample_loss16(r, kk) * sgate[wv][s];
        wl += __shfl_xor(wl, 16, 64);
        wl += __shfl_xor(wl, 32, 64);
        if (lane == 0) part_store(&partials[b * 2 + wv], wl);
    }
}

extern "C" void kernel_launch(void* const* d_in, const int* in_sizes, int n_in,
                              void* d_out, int out_size, void* d_ws, size_t ws_size,
                              hipStream_t stream)
{
    const float* x       = (const float*)d_in[0];
    const int*   labels  = (const int*)  d_in[1];
    const float* centers = (const float*)d_in[2];
    float*       out     = (float*)d_out;
    char*        ws      = (char*)d_ws;

    int*   counts = (int*)  (ws + OFF_COUNTS);
    int*   lists  = (int*)  (ws + OFF_LISTS);
    float* parts  = (float*)(ws + OFF_PART);

    bin_split<<<C_CLS * 2, 256, 0, stream>>>(labels, counts, lists, parts);
    quad_dots<<<NBLK + 1,  256, 0, stream>>>(x, centers, counts, lists, parts, out);
}